// Round 4
// baseline (452.835 us; speedup 1.0000x reference)
//
#include <hip/hip_runtime.h>
#include <hip/hip_bf16.h>
#include <math.h>

// B,T,D,H = 64,2048,256,5
constexpr int BB   = 64;
constexpr int TT   = 2048;
constexpr int DD   = 256;
constexpr int HH   = 5;
constexpr int SEG  = 64;             // segments per batch row
constexpr int TSEG = TT / SEG;       // 32 timesteps per block
constexpr int PSTR = 260;            // partial row stride (floats): [0]=l, [1+d]=acc
constexpr size_t CNT_OFF = (size_t)BB * SEG * PSTR * 4;  // counters after part[]

// fast tanh: 1 - 2/(e^{2x}+1). |err| ~1e-6, threshold is 1.7e-3.
__device__ __forceinline__ float ftanh(float x) {
    float e = __expf(2.0f * x);
    return 1.0f - 2.0f * __builtin_amdgcn_rcpf(e + 1.0f);
}

// One block = (b, 32-timestep segment). x register-resident end-to-end.
// |intermed| <= sum_h |uwr[h]| ~ 1, so exp() cannot overflow -> softmax
// WITHOUT max-shift: partials are pure sums (l, acc[256]). The last block
// per batch row (device-scope counter) merges all 64 partials and writes out.
__global__ __launch_bounds__(256, 3)
void seg_kernel(const float* __restrict__ x_temp,
                const float* __restrict__ x_fea,
                const int* __restrict__ mask,            // bool -> int32 per harness
                const float* __restrict__ W_temp,        // (D,H) row-major
                const float* __restrict__ b_temp,
                const float* __restrict__ W_fea,         // (1,H)
                const float* __restrict__ b_fea,
                const float* __restrict__ uw,            // (H,H)
                float* __restrict__ part,                // (B*SEG, PSTR)
                int* __restrict__ cnt,                   // (B,) zeroed per call
                float* __restrict__ out)                 // (B, D)
{
    __shared__ alignas(16) float im[2 * TSEG];   // interleaved {intermed, maskf}
    __shared__ alignas(16) float ldsw[8 * 264];  // per-(wave,half) acc partials
    __shared__ int lastflag;

    const int tid  = threadIdx.x;
    const int l    = tid & 63;
    const int wave = tid >> 6;
    const int half = l >> 5;
    const int l32  = l & 31;
    const int blk  = blockIdx.x;
    const int b    = blk >> 6;          // blk / SEG
    const int seg  = blk & (SEG - 1);
    const int t0   = seg * TSEG;
    const size_t rowbase = (size_t)b * TT;
    const float* xbase = x_temp + (rowbase + t0) * (size_t)DD;

    if (tid < TSEG) im[2 * tid + 1] = mask[rowbase + t0 + tid] ? 1.0f : 0.0f;

    // ---- stage: 4 row-groups x 8 floats per lane, straight into registers ----
    const int dbase = l32 * 8;
    float4 xq[4][2];
#pragma unroll
    for (int it = 0; it < 4; ++it) {
        const float* p = xbase + it * (8 * DD) + wave * (2 * DD) + half * DD + dbase;
        xq[it][0] = *(const float4*)(p);
        xq[it][1] = *(const float4*)(p + 4);
    }

    float wv[8][HH];
#pragma unroll
    for (int e = 0; e < 8; ++e)
#pragma unroll
        for (int h = 0; h < HH; ++h)
            wv[e][h] = W_temp[(dbase + e) * HH + h];

    float wfea[HH], bfea[HH], btmp[HH], uwr[HH];
#pragma unroll
    for (int h = 0; h < HH; ++h) {
        wfea[h] = W_fea[h]; bfea[h] = b_fea[h]; btmp[h] = b_temp[h];
        float s = 0.f;
#pragma unroll
        for (int h2 = 0; h2 < HH; ++h2) s += uw[h * HH + h2];
        uwr[h] = s;  // sum(hadamard@uw+b,-1) = hadamard.uwr + const (cancels in softmax)
    }

    // ---- dot + 32-lane butterfly + intermed, one row per (it,wave,half) ----
#pragma unroll
    for (int it = 0; it < 4; ++it) {
        const int r = it * 8 + wave * 2 + half;
        const float4 a0 = xq[it][0], a1 = xq[it][1];
        float ph[HH];
#pragma unroll
        for (int h = 0; h < HH; ++h)
            ph[h] = a0.x * wv[0][h] + a0.y * wv[1][h] + a0.z * wv[2][h] + a0.w * wv[3][h]
                  + a1.x * wv[4][h] + a1.y * wv[5][h] + a1.z * wv[6][h] + a1.w * wv[7][h];
#pragma unroll
        for (int off = 16; off >= 1; off >>= 1)
#pragma unroll
            for (int h = 0; h < HH; ++h)
                ph[h] += __shfl_xor(ph[h], off);

        const float xf = x_fea[rowbase + t0 + r];
        float inter = 0.f;
#pragma unroll
        for (int h = 0; h < HH; ++h)
            inter += ftanh(ph[h] + btmp[h]) * ftanh(xf * wfea[h] + bfea[h]) * uwr[h];
        if (l32 == 0) im[2 * r] = inter;
    }
    __syncthreads();

    // ---- l = sum of masked exp (no max-shift; args bounded by ~1) ----
    float lsum = 0.f;
#pragma unroll
    for (int k = 0; k < 16; ++k) {
        float4 v = *(const float4*)(&im[4 * k]);   // {i_2k, m_2k, i_2k+1, m_2k+1}
        lsum += v.y * __expf(v.x) + v.w * __expf(v.z);
    }

    // ---- weighted accumulation from registers ----
    float acc8[8] = {0.f, 0.f, 0.f, 0.f, 0.f, 0.f, 0.f, 0.f};
#pragma unroll
    for (int it = 0; it < 4; ++it) {
        const int r = it * 8 + wave * 2 + half;
        const float w = im[2 * r + 1] * __expf(im[2 * r]);
        const float4 a0 = xq[it][0], a1 = xq[it][1];
        acc8[0] = fmaf(w, a0.x, acc8[0]); acc8[1] = fmaf(w, a0.y, acc8[1]);
        acc8[2] = fmaf(w, a0.z, acc8[2]); acc8[3] = fmaf(w, a0.w, acc8[3]);
        acc8[4] = fmaf(w, a1.x, acc8[4]); acc8[5] = fmaf(w, a1.y, acc8[5]);
        acc8[6] = fmaf(w, a1.z, acc8[6]); acc8[7] = fmaf(w, a1.w, acc8[7]);
    }

    // ---- merge 8 (wave,half) slots via LDS ----
    const int slot = wave * 2 + half;
    float* wp = &ldsw[slot * 264 + dbase];
    *(float4*)(wp)     = make_float4(acc8[0], acc8[1], acc8[2], acc8[3]);
    *(float4*)(wp + 4) = make_float4(acc8[4], acc8[5], acc8[6], acc8[7]);
    __syncthreads();

    float accd = 0.f;
#pragma unroll
    for (int s = 0; s < 8; ++s) accd += ldsw[s * 264 + tid];

    // ---- publish partial, then last-block-per-row combines ----
    float* pb = part + (size_t)blk * PSTR;
    pb[1 + tid] = accd;
    if (tid == 0) pb[0] = lsum;
    __syncthreads();                    // drains this block's stores (vmcnt 0)
    if (tid == 0) {
        __threadfence();                // release: partials visible device-wide
        int prev = atomicAdd(&cnt[b], 1);   // device-scope by default
        lastflag = (prev == SEG - 1);
    }
    __syncthreads();
    if (lastflag) {
        __threadfence();                // acquire: see other XCDs' partials
        const float* base = part + (size_t)b * SEG * PSTR;
        float den = 0.f, num = 0.f;
#pragma unroll 8
        for (int s = 0; s < SEG; ++s) {
            const float* p = base + (size_t)s * PSTR;
            den += p[0];                // broadcast read
            num += p[1 + tid];          // coalesced
        }
        out[(size_t)b * DD + tid] = num / den;
    }
}

extern "C" void kernel_launch(void* const* d_in, const int* in_sizes, int n_in,
                              void* d_out, int out_size, void* d_ws, size_t ws_size,
                              hipStream_t stream) {
    const float* x_temp = (const float*)d_in[0];
    const float* x_fea  = (const float*)d_in[1];
    const int*   mask   = (const int*)d_in[2];
    const float* W_temp = (const float*)d_in[3];
    const float* b_temp = (const float*)d_in[4];
    const float* W_fea  = (const float*)d_in[5];
    const float* b_fea  = (const float*)d_in[6];
    // d_in[7] = b : constant across T, cancels in softmax — unused.
    const float* uw     = (const float*)d_in[8];

    float* part = (float*)d_ws;                       // 4096 x 260 floats ~4.26 MB
    int*   cnt  = (int*)((char*)d_ws + CNT_OFF);      // 64 ints
    float* out  = (float*)d_out;

    hipMemsetAsync(cnt, 0, BB * sizeof(int), stream); // ws is poisoned 0xAA each call
    seg_kernel<<<BB * SEG, 256, 0, stream>>>(x_temp, x_fea, mask, W_temp,
                                             b_temp, W_fea, b_fea, uw,
                                             part, cnt, out);
}

// Round 5
// 209.340 us; speedup vs baseline: 2.1632x; 2.1632x over previous
//
#include <hip/hip_runtime.h>
#include <hip/hip_bf16.h>
#include <math.h>

// B,T,D,H = 64,2048,256,5
constexpr int BB   = 64;
constexpr int TT   = 2048;
constexpr int DD   = 256;
constexpr int HH   = 5;
constexpr int SEG  = 64;             // segments per batch row
constexpr int TSEG = TT / SEG;       // 32 timesteps per block
constexpr int PSTR = 260;            // partial row stride (floats): [0]=l, [1+d]=acc

// fast tanh: 1 - 2/(e^{2x}+1). |err| ~1e-6, threshold is 1.7e-3.
__device__ __forceinline__ float ftanh(float x) {
    float e = __expf(2.0f * x);
    return 1.0f - 2.0f * __builtin_amdgcn_rcpf(e + 1.0f);
}

// One block = (b, 32-timestep segment). x register-resident end-to-end.
// |intermed| <= sum_h |uwr[h]| ~ 0.6, so exp() cannot overflow -> softmax
// WITHOUT max-shift: partials are pure sums (l, acc[256]). The reference's
// softmax->mask->renorm makes the unmasked denominator cancel, so we only
// need l = sum(m*e^i) and acc = sum(m*e^i*x). Cross-segment merge in a
// second kernel (kernel boundary = one L2 writeback, NOT per-block fences:
// R4 showed per-block __threadfence costs +230us on gfx950's split L2s).
__global__ __launch_bounds__(256, 3)
void seg_kernel(const float* __restrict__ x_temp,
                const float* __restrict__ x_fea,
                const int* __restrict__ mask,            // bool -> int32 per harness
                const float* __restrict__ W_temp,        // (D,H) row-major
                const float* __restrict__ b_temp,
                const float* __restrict__ W_fea,         // (1,H)
                const float* __restrict__ b_fea,
                const float* __restrict__ uw,            // (H,H)
                float* __restrict__ part)                // (B*SEG, PSTR)
{
    __shared__ alignas(16) float im[2 * TSEG];   // interleaved {intermed, maskf}
    __shared__ alignas(16) float ldsw[8 * 264];  // per-(wave,half) acc partials

    const int tid  = threadIdx.x;
    const int l    = tid & 63;
    const int wave = tid >> 6;
    const int half = l >> 5;
    const int l32  = l & 31;
    const int blk  = blockIdx.x;
    const int b    = blk >> 6;          // blk / SEG
    const int seg  = blk & (SEG - 1);
    const int t0   = seg * TSEG;
    const size_t rowbase = (size_t)b * TT;
    const float* xbase = x_temp + (rowbase + t0) * (size_t)DD;

    if (tid < TSEG) im[2 * tid + 1] = mask[rowbase + t0 + tid] ? 1.0f : 0.0f;

    // ---- stage: 4 row-groups x 8 floats per lane, straight into registers ----
    const int dbase = l32 * 8;
    float4 xq[4][2];
#pragma unroll
    for (int it = 0; it < 4; ++it) {
        const float* p = xbase + it * (8 * DD) + wave * (2 * DD) + half * DD + dbase;
        xq[it][0] = *(const float4*)(p);
        xq[it][1] = *(const float4*)(p + 4);
    }

    float wv[8][HH];
#pragma unroll
    for (int e = 0; e < 8; ++e)
#pragma unroll
        for (int h = 0; h < HH; ++h)
            wv[e][h] = W_temp[(dbase + e) * HH + h];

    float wfea[HH], bfea[HH], btmp[HH], uwr[HH];
#pragma unroll
    for (int h = 0; h < HH; ++h) {
        wfea[h] = W_fea[h]; bfea[h] = b_fea[h]; btmp[h] = b_temp[h];
        float s = 0.f;
#pragma unroll
        for (int h2 = 0; h2 < HH; ++h2) s += uw[h * HH + h2];
        uwr[h] = s;  // sum(hadamard@uw+b,-1) = hadamard.uwr + const (cancels in softmax)
    }

    // ---- dot + 32-lane butterfly + intermed, one row per (it,wave,half) ----
#pragma unroll
    for (int it = 0; it < 4; ++it) {
        const int r = it * 8 + wave * 2 + half;
        const float4 a0 = xq[it][0], a1 = xq[it][1];
        float ph[HH];
#pragma unroll
        for (int h = 0; h < HH; ++h)
            ph[h] = a0.x * wv[0][h] + a0.y * wv[1][h] + a0.z * wv[2][h] + a0.w * wv[3][h]
                  + a1.x * wv[4][h] + a1.y * wv[5][h] + a1.z * wv[6][h] + a1.w * wv[7][h];
#pragma unroll
        for (int off = 16; off >= 1; off >>= 1)
#pragma unroll
            for (int h = 0; h < HH; ++h)
                ph[h] += __shfl_xor(ph[h], off);   // stays within the 32-lane half

        const float xf = x_fea[rowbase + t0 + r];
        float inter = 0.f;
#pragma unroll
        for (int h = 0; h < HH; ++h)
            inter += ftanh(ph[h] + btmp[h]) * ftanh(xf * wfea[h] + bfea[h]) * uwr[h];
        if (l32 == 0) im[2 * r] = inter;
    }
    __syncthreads();

    // ---- l = sum of masked exp (no max-shift; args bounded by ~0.6) ----
    float lsum = 0.f;
#pragma unroll
    for (int k = 0; k < 16; ++k) {
        float4 v = *(const float4*)(&im[4 * k]);   // {i_2k, m_2k, i_2k+1, m_2k+1}
        lsum += v.y * __expf(v.x) + v.w * __expf(v.z);
    }

    // ---- weighted accumulation from registers ----
    float acc8[8] = {0.f, 0.f, 0.f, 0.f, 0.f, 0.f, 0.f, 0.f};
#pragma unroll
    for (int it = 0; it < 4; ++it) {
        const int r = it * 8 + wave * 2 + half;
        const float w = im[2 * r + 1] * __expf(im[2 * r]);
        const float4 a0 = xq[it][0], a1 = xq[it][1];
        acc8[0] = fmaf(w, a0.x, acc8[0]); acc8[1] = fmaf(w, a0.y, acc8[1]);
        acc8[2] = fmaf(w, a0.z, acc8[2]); acc8[3] = fmaf(w, a0.w, acc8[3]);
        acc8[4] = fmaf(w, a1.x, acc8[4]); acc8[5] = fmaf(w, a1.y, acc8[5]);
        acc8[6] = fmaf(w, a1.z, acc8[6]); acc8[7] = fmaf(w, a1.w, acc8[7]);
    }

    // ---- merge 8 (wave,half) slots via LDS ----
    const int slot = wave * 2 + half;
    float* wp = &ldsw[slot * 264 + dbase];
    *(float4*)(wp)     = make_float4(acc8[0], acc8[1], acc8[2], acc8[3]);
    *(float4*)(wp + 4) = make_float4(acc8[4], acc8[5], acc8[6], acc8[7]);
    __syncthreads();

    float accd = 0.f;
#pragma unroll
    for (int s = 0; s < 8; ++s) accd += ldsw[s * 264 + tid];

    float* pb = part + (size_t)blk * PSTR;
    if (tid == 0) pb[0] = lsum;
    pb[1 + tid] = accd;
}

// Merge SEG partials per batch row. Pure sums (no exp, no max-shift).
__global__ __launch_bounds__(256)
void combine_kernel(const float* __restrict__ part, float* __restrict__ out)
{
    const int b = blockIdx.x;
    const int d = threadIdx.x;
    const float* base = part + (size_t)b * SEG * PSTR;
    float den = 0.f, num = 0.f;
#pragma unroll 8
    for (int s = 0; s < SEG; ++s) {
        const float* p = base + (size_t)s * PSTR;
        den += p[0];          // broadcast read
        num += p[1 + d];      // coalesced
    }
    out[(size_t)b * DD + d] = num / den;
}

extern "C" void kernel_launch(void* const* d_in, const int* in_sizes, int n_in,
                              void* d_out, int out_size, void* d_ws, size_t ws_size,
                              hipStream_t stream) {
    const float* x_temp = (const float*)d_in[0];
    const float* x_fea  = (const float*)d_in[1];
    const int*   mask   = (const int*)d_in[2];
    const float* W_temp = (const float*)d_in[3];
    const float* b_temp = (const float*)d_in[4];
    const float* W_fea  = (const float*)d_in[5];
    const float* b_fea  = (const float*)d_in[6];
    // d_in[7] = b : constant across T, cancels in softmax — unused.
    const float* uw     = (const float*)d_in[8];

    float* part = (float*)d_ws;   // 4096 x 260 floats ~4.26 MB
    float* out  = (float*)d_out;

    seg_kernel<<<BB * SEG, 256, 0, stream>>>(x_temp, x_fea, mask, W_temp,
                                             b_temp, W_fea, b_fea, uw, part);
    combine_kernel<<<BB, DD, 0, stream>>>(part, out);
}

// Round 7
// 207.169 us; speedup vs baseline: 2.1858x; 1.0105x over previous
//
#include <hip/hip_runtime.h>
#include <hip/hip_bf16.h>
#include <math.h>

// B,T,D,H = 64,2048,256,5
constexpr int BB   = 64;
constexpr int TT   = 2048;
constexpr int DD   = 256;
constexpr int HH   = 5;
constexpr int SEG  = 64;             // segments per batch row
constexpr int TSEG = TT / SEG;       // 32 timesteps per block
constexpr int PSTR = 260;            // partial row stride: [0]=l, [1+d]=acc

// fast tanh: 1 - 2/(e^{2x}+1). |err| ~1e-6, threshold is 1.7e-3.
__device__ __forceinline__ float ftanh(float x) {
    float e = __expf(2.0f * x);
    return 1.0f - 2.0f * __builtin_amdgcn_rcpf(e + 1.0f);
}

// DPP add: x += dpp_shifted(x). Runs on the VALU pipe (vs __shfl_xor ->
// ds_swizzle on the single per-CU LDS pipe shared by all resident waves).
// dpp_ctrl must be an immediate -> template parameter.
template <int CTRL>
__device__ __forceinline__ float dpp_add(float x) {
    int s = __builtin_amdgcn_update_dpp(0, __float_as_int(x), CTRL, 0xf, 0xf, true);
    return x + __int_as_float(s);
}
// 32-lane-half sum via row_shr 1/2/4/8 + row_bcast15. Valid in lanes 31 and 63.
__device__ __forceinline__ float half_sum_dpp(float v) {
    v = dpp_add<0x111>(v);   // row_shr:1
    v = dpp_add<0x112>(v);   // row_shr:2
    v = dpp_add<0x114>(v);   // row_shr:4
    v = dpp_add<0x118>(v);   // row_shr:8  -> lane15/31/47/63 = 16-row sums
    v = dpp_add<0x142>(v);   // row_bcast15 -> lane31 = sum(0..31), lane63 = sum(32..63)
    return v;
}

// One block = (b, 32-timestep segment). x register-resident end-to-end.
// |intermed| <= sum|uwr| ~ 0.5 -> softmax WITHOUT max-shift; partials are
// pure sums. Cross-segment merge in a second kernel (kernel boundary does
// the L2 writeback once — R4 showed per-block device fences cost +230us).
__global__ __launch_bounds__(256, 4)
void seg_kernel(const float* __restrict__ x_temp,
                const float* __restrict__ x_fea,
                const int* __restrict__ mask,            // bool -> int32 per harness
                const float* __restrict__ W_temp,        // (D,H) row-major
                const float* __restrict__ b_temp,
                const float* __restrict__ W_fea,         // (1,H)
                const float* __restrict__ b_fea,
                const float* __restrict__ uw,            // (H,H)
                float* __restrict__ part)                // (B*SEG, PSTR)
{
    __shared__ alignas(16) float im[2 * TSEG];   // interleaved {intermed, maskf}
    __shared__ alignas(16) float ldsw[8 * 264];  // per-(wave,half) acc partials

    const int tid  = threadIdx.x;
    const int l    = tid & 63;
    const int wave = tid >> 6;
    const int half = l >> 5;
    const int l32  = l & 31;
    const int blk  = blockIdx.x;
    const int b    = blk >> 6;          // blk / SEG
    const int seg  = blk & (SEG - 1);
    const int t0   = seg * TSEG;
    const size_t rowbase = (size_t)b * TT;
    const float* xbase = x_temp + (rowbase + t0) * (size_t)DD;

    if (tid < TSEG) im[2 * tid + 1] = mask[rowbase + t0 + tid] ? 1.0f : 0.0f;

    // ---- stage: 4 row-groups x 8 floats per lane, straight into registers ----
    const int dbase = l32 * 8;
    float4 xq[4][2];
#pragma unroll
    for (int it = 0; it < 4; ++it) {
        const float* p = xbase + it * (8 * DD) + wave * (2 * DD) + half * DD + dbase;
        xq[it][0] = *(const float4*)(p);
        xq[it][1] = *(const float4*)(p + 4);
    }

    float wv[8][HH];
#pragma unroll
    for (int e = 0; e < 8; ++e)
#pragma unroll
        for (int h = 0; h < HH; ++h)
            wv[e][h] = W_temp[(dbase + e) * HH + h];

    float wfea[HH], bfea[HH], btmp[HH], uwr[HH];
#pragma unroll
    for (int h = 0; h < HH; ++h) {
        wfea[h] = W_fea[h]; bfea[h] = b_fea[h]; btmp[h] = b_temp[h];
        float s = 0.f;
#pragma unroll
        for (int h2 = 0; h2 < HH; ++h2) s += uw[h * HH + h2];
        uwr[h] = s;  // sum(hadamard@uw+b,-1) = hadamard.uwr + const (cancels in softmax)
    }

    // ---- dot + DPP 32-half reduce + intermed, one row per (it,wave,half) ----
#pragma unroll
    for (int it = 0; it < 4; ++it) {
        const int r = it * 8 + wave * 2 + half;
        const float4 a0 = xq[it][0], a1 = xq[it][1];
        float ph[HH];
#pragma unroll
        for (int h = 0; h < HH; ++h)
            ph[h] = a0.x * wv[0][h] + a0.y * wv[1][h] + a0.z * wv[2][h] + a0.w * wv[3][h]
                  + a1.x * wv[4][h] + a1.y * wv[5][h] + a1.z * wv[6][h] + a1.w * wv[7][h];
#pragma unroll
        for (int h = 0; h < HH; ++h)
            ph[h] = half_sum_dpp(ph[h]);          // valid in lanes 31 / 63

        if (l32 == 31) {                          // lanes 31 & 63: rows for half 0/1
            const float xf = x_fea[rowbase + t0 + r];
            float inter = 0.f;
#pragma unroll
            for (int h = 0; h < HH; ++h)
                inter += ftanh(ph[h] + btmp[h]) * ftanh(xf * wfea[h] + bfea[h]) * uwr[h];
            im[2 * r] = inter;
        }
    }
    __syncthreads();

    // ---- l = sum of masked exp (no max-shift; args bounded by ~0.5) ----
    float lsum = 0.f;
#pragma unroll
    for (int k = 0; k < 16; ++k) {
        float4 v = *(const float4*)(&im[4 * k]);   // {i_2k, m_2k, i_2k+1, m_2k+1}
        lsum += v.y * __expf(v.x) + v.w * __expf(v.z);
    }

    // ---- weighted accumulation from registers ----
    float acc8[8] = {0.f, 0.f, 0.f, 0.f, 0.f, 0.f, 0.f, 0.f};
#pragma unroll
    for (int it = 0; it < 4; ++it) {
        const int r = it * 8 + wave * 2 + half;
        const float w = im[2 * r + 1] * __expf(im[2 * r]);
        const float4 a0 = xq[it][0], a1 = xq[it][1];
        acc8[0] = fmaf(w, a0.x, acc8[0]); acc8[1] = fmaf(w, a0.y, acc8[1]);
        acc8[2] = fmaf(w, a0.z, acc8[2]); acc8[3] = fmaf(w, a0.w, acc8[3]);
        acc8[4] = fmaf(w, a1.x, acc8[4]); acc8[5] = fmaf(w, a1.y, acc8[5]);
        acc8[6] = fmaf(w, a1.z, acc8[6]); acc8[7] = fmaf(w, a1.w, acc8[7]);
    }

    // ---- merge 8 (wave,half) slots via LDS ----
    const int slot = wave * 2 + half;
    float* wp = &ldsw[slot * 264 + dbase];
    *(float4*)(wp)     = make_float4(acc8[0], acc8[1], acc8[2], acc8[3]);
    *(float4*)(wp + 4) = make_float4(acc8[4], acc8[5], acc8[6], acc8[7]);
    __syncthreads();

    float accd = 0.f;
#pragma unroll
    for (int s = 0; s < 8; ++s) accd += ldsw[s * 264 + tid];

    float* pb = part + (size_t)blk * PSTR;
    if (tid == 0) pb[0] = lsum;
    pb[1 + tid] = accd;
}

// Merge SEG partials per batch row. Pure sums (no exp, no max-shift).
__global__ __launch_bounds__(256)
void combine_kernel(const float* __restrict__ part, float* __restrict__ out)
{
    const int b = blockIdx.x;
    const int d = threadIdx.x;
    const float* base = part + (size_t)b * SEG * PSTR;
    float den = 0.f, num = 0.f;
#pragma unroll 8
    for (int s = 0; s < SEG; ++s) {
        const float* p = base + (size_t)s * PSTR;
        den += p[0];          // broadcast read
        num += p[1 + d];      // coalesced
    }
    out[(size_t)b * DD + d] = num / den;
}

extern "C" void kernel_launch(void* const* d_in, const int* in_sizes, int n_in,
                              void* d_out, int out_size, void* d_ws, size_t ws_size,
                              hipStream_t stream) {
    const float* x_temp = (const float*)d_in[0];
    const float* x_fea  = (const float*)d_in[1];
    const int*   mask   = (const int*)d_in[2];
    const float* W_temp = (const float*)d_in[3];
    const float* b_temp = (const float*)d_in[4];
    const float* W_fea  = (const float*)d_in[5];
    const float* b_fea  = (const float*)d_in[6];
    // d_in[7] = b : constant across T, cancels in softmax — unused.
    const float* uw     = (const float*)d_in[8];

    float* part = (float*)d_ws;   // 4096 x 260 floats ~4.26 MB
    float* out  = (float*)d_out;

    seg_kernel<<<BB * SEG, 256, 0, stream>>>(x_temp, x_fea, mask, W_temp,
                                             b_temp, W_fea, b_fea, uw, part);
    combine_kernel<<<BB, DD, 0, stream>>>(part, out);
}